// Round 7
// baseline (1787.028 us; speedup 1.0000x reference)
//
#include <hip/hip_runtime.h>
#include <hip/hip_bf16.h>
#include <math.h>

#define FEAT 1040
#define NHEAD 8
#define DHEAD 130
#define NLAYER 3
#define NGRAPH 64
#define NEG_SLOPE 0.2f
#define BN_EPS 1e-5f
#define KP 1056   // FEAT padded to multiple of 32 (K of GEMM)
#define NP 1152   // FEAT padded to multiple of 128; rows 1040..1055 of Bt = wa_src/wa_dst

typedef float floatx4 __attribute__((ext_vector_type(4)));
typedef short shortx8 __attribute__((ext_vector_type(8)));

__device__ __forceinline__ short f2bf(float f) {
    unsigned u = __float_as_uint(f);
    u += 0x7fff + ((u >> 16) & 1);   // round-to-nearest-even
    return (short)(u >> 16);
}
__device__ __forceinline__ float bf2f(short b) {
    return __uint_as_float(((unsigned)(unsigned short)b) << 16);
}

__device__ __forceinline__ void async16(const void* g, void* l) {
    __builtin_amdgcn_global_load_lds(
        (const __attribute__((address_space(1))) unsigned int*)g,
        (__attribute__((address_space(3))) unsigned int*)l, 16, 0, 0);
}

// ---------------- bf16 MFMA GEMM: A staged in LDS (dbuf), B direct from L2 ----
// XCD swizzle: the 9 bni-tiles of one bmi land on the same XCD consecutively.
__global__ __launch_bounds__(256) void gemm_mfma(const short* __restrict__ A,
                                                 const short* __restrict__ Bt,
                                                 short* __restrict__ xh_bf,
                                                 float* __restrict__ asrc,
                                                 float* __restrict__ adst,
                                                 int M, int MT) {
    const int lid = blockIdx.x;
    const int g = lid / 72, r = lid % 72;
    const int bmi = g * 8 + (r & 7);
    const int bni = r >> 3;
    if (bmi >= MT) return;
    const int bm = bmi * 128;
    const int bn = bni * 128;

    __shared__ short As[2][4096];   // 128x32 A tile, double-buffered (16 KB)
    const int tid = threadIdx.x;
    const int lane = tid & 63;
    const int w = tid >> 6;
    const int wm = (w & 1) * 64;
    const int wn = (w >> 1) * 64;

    // A staging decode: 512 slots of 16B cover 128 rows x 32 k
    const int tt0 = tid, tt1 = 256 + tid;
    const int row0 = ((tt0 >> 6) << 4) | (tt0 & 15);
    const int col0 = ((tt0 >> 4) & 3) * 8;
    const int row1 = ((tt1 >> 6) << 4) | (tt1 & 15);
    const int col1 = ((tt1 >> 4) & 3) * 8;
    const short* gA0 = A + (size_t)(bm + row0) * KP + col0;
    const short* gA1 = A + (size_t)(bm + row1) * KP + col1;

    const int fr = lane & 15;
    const int kq = lane >> 4;

    // B fragment base: lane reads Bt[bn+wn+j*16+fr][kq*8 + k0 .. +8]
    const short* gBf = Bt + (size_t)(bn + wn + fr) * KP + (kq << 3);

    floatx4 acc[4][4];
#pragma unroll
    for (int i = 0; i < 4; i++)
#pragma unroll
        for (int j = 0; j < 4; j++) acc[i][j] = (floatx4){0.f, 0.f, 0.f, 0.f};

    shortx8 bcur[4], bnxt[4];
#pragma unroll
    for (int j = 0; j < 4; j++) bcur[j] = *(const shortx8*)(gBf + (size_t)j * 16 * KP);

    async16(gA0, &As[0][tt0 * 8]);
    async16(gA1, &As[0][tt1 * 8]);
    __syncthreads();

    int cur = 0;
    for (int k0 = 0; k0 < KP; k0 += 32) {
        const int nxt = cur ^ 1;
        const int k1 = k0 + 32;
        if (k1 < KP) {
            async16(gA0 + k1, &As[nxt][tt0 * 8]);
            async16(gA1 + k1, &As[nxt][tt1 * 8]);
#pragma unroll
            for (int j = 0; j < 4; j++)
                bnxt[j] = *(const shortx8*)(gBf + (size_t)j * 16 * KP + k1);
        }
        shortx8 af[4];
#pragma unroll
        for (int i = 0; i < 4; i++)
            af[i] = *(const shortx8*)&As[cur][((wm >> 4) + i) * 512 + kq * 128 + fr * 8];
#pragma unroll
        for (int i = 0; i < 4; i++)
#pragma unroll
            for (int j = 0; j < 4; j++)
                acc[i][j] = __builtin_amdgcn_mfma_f32_16x16x32_bf16(af[i], bcur[j], acc[i][j], 0, 0, 0);
        __syncthreads();
        cur = nxt;
#pragma unroll
        for (int j = 0; j < 4; j++) bcur[j] = bnxt[j];
    }

    // C/D layout: col = lane&15, row = (lane>>4)*4 + reg
    const int rbase = (lane >> 4) * 4;
    const int ccol = lane & 15;
#pragma unroll
    for (int j = 0; j < 4; j++) {
        int colbase = bn + wn + j * 16;
        if (colbase < FEAT) {
            int col = colbase + ccol;
#pragma unroll
            for (int i = 0; i < 4; i++)
#pragma unroll
                for (int r2 = 0; r2 < 4; r2++) {
                    int row = bm + wm + i * 16 + rbase + r2;
                    if (row < M) xh_bf[(size_t)row * FEAT + col] = f2bf(acc[i][j][r2]);
                }
        } else if (colbase == FEAT) {
            int c = ccol;
            float* tgt = (c < 8) ? asrc : adst;
            int h = c & 7;
#pragma unroll
            for (int i = 0; i < 4; i++)
#pragma unroll
                for (int r2 = 0; r2 < 4; r2++) {
                    int row = bm + wm + i * 16 + rbase + r2;
                    if (row < M) tgt[(size_t)row * NHEAD + h] = acc[i][j][r2];
                }
        }
    }
}

// ---------------- conversions / padding ----------------
__global__ void conv_x_bf(const float* __restrict__ x, short* __restrict__ out, int N) {
    int idx = blockIdx.x * 256 + threadIdx.x;
    if (idx >= N * FEAT) return;
    int r = idx / FEAT, c = idx - r * FEAT;
    out[(size_t)r * KP + c] = f2bf(x[idx]);
}

__global__ void pad_bf(short* __restrict__ buf, int Mvalid) {
    int r = blockIdx.x;
    short* row = buf + (size_t)r * KP;
    if (r < Mvalid) {
        if (threadIdx.x < KP - FEAT) row[FEAT + threadIdx.x] = 0;
    } else {
        for (int c = threadIdx.x; c < KP; c += 64) row[c] = 0;
    }
}

// Bt3[l][n][k] = bf16(W[l][k][n]) via LDS tile transpose (3-D grid, z = layer)
__global__ void transpose_w(const float* __restrict__ W, short* __restrict__ Bt3) {
    __shared__ float t[32][33];
    int l = blockIdx.z;
    const float* Wl = W + (size_t)l * FEAT * FEAT;
    short* Bt = Bt3 + (size_t)l * NP * KP;
    int kb = blockIdx.x * 32, nb = blockIdx.y * 32;
    int tx = threadIdx.x & 31, ty = threadIdx.x >> 5;
#pragma unroll
    for (int i = 0; i < 4; i++) {
        int k = kb + ty + i * 8, n = nb + tx;
        t[ty + i * 8][tx] = (k < FEAT && n < FEAT) ? Wl[(size_t)k * FEAT + n] : 0.f;
    }
    __syncthreads();
#pragma unroll
    for (int i = 0; i < 4; i++) {
        int n = nb + ty + i * 8, k = kb + tx;
        if (n < FEAT && k < FEAT) Bt[(size_t)n * KP + k] = f2bf(t[tx][ty + i * 8]);
    }
}

__global__ void wa_kernel(const float* __restrict__ W, const float* __restrict__ a_s,
                          const float* __restrict__ a_d, short* __restrict__ Bt3) {
    int t = blockIdx.x * 256 + threadIdx.x;
    if (t >= NLAYER * FEAT * NHEAD) return;
    int h = t & 7;
    int f = (t >> 3) % FEAT;
    int l = t / (FEAT * NHEAD);
    const float* wrow = W + (((size_t)l * FEAT + f) * NHEAD + h) * DHEAD;
    const float* as = a_s + ((size_t)l * NHEAD + h) * DHEAD;
    const float* ad = a_d + ((size_t)l * NHEAD + h) * DHEAD;
    float ws = 0.f, wd = 0.f;
    for (int d = 0; d < DHEAD; d++) {
        float wv = wrow[d];
        ws += wv * as[d];
        wd += wv * ad[d];
    }
    short* base = Bt3 + (size_t)l * NP * KP;
    base[(size_t)(FEAT + h) * KP + f] = f2bf(ws);
    base[(size_t)(FEAT + 8 + h) * KP + f] = f2bf(wd);
}

// ---------------- graph preprocessing ----------------
__global__ void build_edges(const int* __restrict__ ei, int E, int N,
                            int* __restrict__ src2, int* __restrict__ dst2,
                            int* __restrict__ deg) {
    int e = blockIdx.x * 256 + threadIdx.x;
    int E2 = E + N;
    if (e >= E2) return;
    int s, d;
    if (e < E) { s = ei[e]; d = ei[E + e]; }
    else       { s = e - E; d = e - E; }
    src2[e] = s;
    dst2[e] = d;
    atomicAdd(&deg[d], 1);
}

__global__ void scan_kernel(const int* __restrict__ deg, int* __restrict__ off,
                            int* __restrict__ cursor, int N) {
    __shared__ int wsum[16];
    __shared__ int carry_s;
    int tid = threadIdx.x;
    int lane = tid & 63, wid = tid >> 6;
    if (tid == 0) carry_s = 0;
    __syncthreads();
    for (int base = 0; base < N; base += 1024) {
        int i = base + tid;
        int v = (i < N) ? deg[i] : 0;
        int incl = v;
#pragma unroll
        for (int o = 1; o < 64; o <<= 1) {
            int u = __shfl_up(incl, o);
            if (lane >= o) incl += u;
        }
        if (lane == 63) wsum[wid] = incl;
        __syncthreads();
        if (wid == 0) {
            int wv = (lane < 16) ? wsum[lane] : 0;
            int wincl = wv;
#pragma unroll
            for (int o = 1; o < 16; o <<= 1) {
                int u = __shfl_up(wincl, o);
                if (lane >= o) wincl += u;
            }
            if (lane < 16) wsum[lane] = wincl - wv;
        }
        __syncthreads();
        int excl = carry_s + wsum[wid] + incl - v;
        if (i < N) { off[i] = excl; cursor[i] = excl; }
        int tot = 0;
        if (tid == 1023) tot = wsum[15] + incl;
        __syncthreads();
        if (tid == 1023) carry_s += tot;
        __syncthreads();
    }
    if (threadIdx.x == 0) off[N] = carry_s;
}

__global__ void scatter_k(const int* __restrict__ src2, const int* __restrict__ dst2,
                          int* __restrict__ cursor, int* __restrict__ ssrc, int E2) {
    int e = blockIdx.x * 256 + threadIdx.x;
    if (e >= E2) return;
    int d = dst2[e];
    int pos = atomicAdd(&cursor[d], 1);
    ssrc[pos] = src2[e];
}

__global__ void gstart_k(const int* __restrict__ batch, int* __restrict__ gstart, int N) {
    int n = blockIdx.x * 256 + threadIdx.x;
    if (n >= N) return;
    int b = batch[n];
    if (n == 0) {
        for (int g = 0; g <= b; g++) gstart[g] = 0;
    } else {
        int pb = batch[n - 1];
        for (int g = pb + 1; g <= b; g++) gstart[g] = n;
    }
    if (n == N - 1) {
        for (int g = b + 1; g <= NGRAPH; g++) gstart[g] = N;
    }
}

// ------- fused segment-softmax + aggregation + BN + ReLU -----------------
// 320 threads: waves 0-3 aggregate features (t<256: f0=t*4; t<4 also cover
// 1024+t*4); wave 4 computes the 8-head softmax in chunks of 8 edges
// (lane = edge*8 + head) into double-buffered LDS, overlapping the
// aggregation of the previous chunk. Weights are unnormalized exp(); the
// denominator is folded into the epilogue (logits bounded ~|4|, fp32-safe).
__global__ __launch_bounds__(320) void aggregate(
    const short* __restrict__ xh_bf,
    const int* __restrict__ off, const int* __restrict__ ssrc,
    const float* __restrict__ asrc, const float* __restrict__ adst,
    const float* __restrict__ prev_f,     // fp32 residual (layer 1: x) or null
    const short* __restrict__ prev_bf,    // bf16 residual (layer 2: hA_bf) or null
    const float* __restrict__ b_att, const float* __restrict__ gamma,
    const float* __restrict__ beta, const float* __restrict__ mean,
    const float* __restrict__ var,
    short* __restrict__ hout_bf, int N) {
    __shared__ float pl[2][8][8];   // [buf][edge][head] unnormalized weights
    __shared__ int   srcb[2][8];
    __shared__ float dinv_s[8];

    const int n = blockIdx.x;
    const int s = off[n], e = off[n + 1];
    const int nchunk = (e - s + 7) >> 3;
    const int t = threadIdx.x;
    const bool smwave = (t >= 256);
    const int lane = t & 63;

    // aggregation state
    const int f0 = t * 4;
    int hh[4];
    if (!smwave) {
#pragma unroll
        for (int i = 0; i < 4; i++) hh[i] = (f0 + i) / DHEAD;
    }
    float acc[4] = {0.f, 0.f, 0.f, 0.f};
    float acc2[4] = {0.f, 0.f, 0.f, 0.f};   // t<4: features 1024+t*4 (head 7)
    const int f2 = 1024 + t * 4;

    // softmax state (wave 4)
    const int el = lane >> 3, h = lane & 7;
    float denom = 0.f;
    float ad = 0.f;
    if (smwave) ad = adst[(size_t)n * NHEAD + h];

    for (int c = 0; c < nchunk; c++) {
        const int buf = c & 1;
        if (smwave) {
            int j = s + c * 8 + el;
            float ex = 0.f;
            int sj = 0;
            if (j < e) {
                sj = ssrc[j];
                float v = asrc[(size_t)sj * NHEAD + h] + ad;
                v = (v > 0.f) ? v : NEG_SLOPE * v;
                ex = __expf(v);
            }
            pl[buf][el][h] = ex;
            if (h == 0) srcb[buf][el] = sj;
            denom += ex;
        }
        __syncthreads();
        if (!smwave) {
            int rem = e - (s + c * 8);
            int cnt = rem > 8 ? 8 : rem;
            int sj[8];
            ushort4 v[8], v2[8];
#pragma unroll
            for (int u = 0; u < 8; u++)
                if (u < cnt) sj[u] = srcb[buf][u];
#pragma unroll
            for (int u = 0; u < 8; u++)
                if (u < cnt) v[u] = *(const ushort4*)(xh_bf + (size_t)sj[u] * FEAT + f0);
            if (t < 4) {
#pragma unroll
                for (int u = 0; u < 8; u++)
                    if (u < cnt) v2[u] = *(const ushort4*)(xh_bf + (size_t)sj[u] * FEAT + f2);
            }
#pragma unroll
            for (int u = 0; u < 8; u++) {
                if (u < cnt) {
                    acc[0] += pl[buf][u][hh[0]] * bf2f((short)v[u].x);
                    acc[1] += pl[buf][u][hh[1]] * bf2f((short)v[u].y);
                    acc[2] += pl[buf][u][hh[2]] * bf2f((short)v[u].z);
                    acc[3] += pl[buf][u][hh[3]] * bf2f((short)v[u].w);
                }
            }
            if (t < 4) {
#pragma unroll
                for (int u = 0; u < 8; u++) {
                    if (u < cnt) {
                        float pw = pl[buf][u][7];
                        acc2[0] += pw * bf2f((short)v2[u].x);
                        acc2[1] += pw * bf2f((short)v2[u].y);
                        acc2[2] += pw * bf2f((short)v2[u].z);
                        acc2[3] += pw * bf2f((short)v2[u].w);
                    }
                }
            }
        }
    }

    if (smwave) {
        denom += __shfl_xor(denom, 8);
        denom += __shfl_xor(denom, 16);
        denom += __shfl_xor(denom, 32);
        if (el == 0) dinv_s[h] = 1.0f / denom;
    }
    __syncthreads();
    if (smwave) return;

    // normalize + epilogue, slot 1 (f0)
    {
#pragma unroll
        for (int i = 0; i < 4; i++) acc[i] *= dinv_s[hh[i]];
        float4 bv = *(const float4*)(b_att + f0);
        float4 gv = *(const float4*)(gamma + f0);
        float4 be = *(const float4*)(beta + f0);
        float4 mv = *(const float4*)(mean + f0);
        float4 vv = *(const float4*)(var + f0);
        float z[4] = {acc[0] + bv.x, acc[1] + bv.y, acc[2] + bv.z, acc[3] + bv.w};
        if (prev_f) {
            float4 pv = *(const float4*)(prev_f + (size_t)n * FEAT + f0);
            z[0] += pv.x; z[1] += pv.y; z[2] += pv.z; z[3] += pv.w;
        }
        if (prev_bf) {
            ushort4 pv = *(const ushort4*)(prev_bf + (size_t)n * KP + f0);
            z[0] += bf2f((short)pv.x); z[1] += bf2f((short)pv.y);
            z[2] += bf2f((short)pv.z); z[3] += bf2f((short)pv.w);
        }
        float g4[4] = {gv.x, gv.y, gv.z, gv.w};
        float b4[4] = {be.x, be.y, be.z, be.w};
        float m4[4] = {mv.x, mv.y, mv.z, mv.w};
        float v4[4] = {vv.x, vv.y, vv.z, vv.w};
        ushort4 o;
        unsigned short* op = (unsigned short*)&o;
#pragma unroll
        for (int i = 0; i < 4; i++) {
            float zz = (z[i] - m4[i]) * rsqrtf(v4[i] + BN_EPS) * g4[i] + b4[i];
            op[i] = (unsigned short)f2bf(fmaxf(zz, 0.f));
        }
        *(ushort4*)(hout_bf + (size_t)n * KP + f0) = o;
    }
    // slot 2 (features 1024..1039, threads 0..3, head 7)
    if (t < 4) {
        float dv7 = dinv_s[7];
#pragma unroll
        for (int i = 0; i < 4; i++) acc2[i] *= dv7;
        float4 bv = *(const float4*)(b_att + f2);
        float4 gv = *(const float4*)(gamma + f2);
        float4 be = *(const float4*)(beta + f2);
        float4 mv = *(const float4*)(mean + f2);
        float4 vv = *(const float4*)(var + f2);
        float z[4] = {acc2[0] + bv.x, acc2[1] + bv.y, acc2[2] + bv.z, acc2[3] + bv.w};
        if (prev_f) {
            float4 pv = *(const float4*)(prev_f + (size_t)n * FEAT + f2);
            z[0] += pv.x; z[1] += pv.y; z[2] += pv.z; z[3] += pv.w;
        }
        if (prev_bf) {
            ushort4 pv = *(const ushort4*)(prev_bf + (size_t)n * KP + f2);
            z[0] += bf2f((short)pv.x); z[1] += bf2f((short)pv.y);
            z[2] += bf2f((short)pv.z); z[3] += bf2f((short)pv.w);
        }
        float g4[4] = {gv.x, gv.y, gv.z, gv.w};
        float b4[4] = {be.x, be.y, be.z, be.w};
        float m4[4] = {mv.x, mv.y, mv.z, mv.w};
        float v4[4] = {vv.x, vv.y, vv.z, vv.w};
        ushort4 o;
        unsigned short* op = (unsigned short*)&o;
#pragma unroll
        for (int i = 0; i < 4; i++) {
            float zz = (z[i] - m4[i]) * rsqrtf(v4[i] + BN_EPS) * g4[i] + b4[i];
            op[i] = (unsigned short)f2bf(fmaxf(zz, 0.f));
        }
        *(ushort4*)(hout_bf + (size_t)n * KP + f2) = o;
    }
}

// ---------------- pooling over contiguous node ranges ----------------
__global__ __launch_bounds__(320) void pool_k(const short* __restrict__ h,
                                              const int* __restrict__ gstart,
                                              float* __restrict__ pooled) {
    int g = blockIdx.x;
    int t = threadIdx.x;
    if (t >= 260) return;
    int f0 = t * 4;
    int s = gstart[g], e = gstart[g + 1];
    float acc[4] = {0.f, 0.f, 0.f, 0.f};
    int n = s;
    for (; n + 4 <= e; n += 4) {
        ushort4 v0 = *(const ushort4*)(h + (size_t)n * KP + f0);
        ushort4 v1 = *(const ushort4*)(h + (size_t)(n + 1) * KP + f0);
        ushort4 v2 = *(const ushort4*)(h + (size_t)(n + 2) * KP + f0);
        ushort4 v3 = *(const ushort4*)(h + (size_t)(n + 3) * KP + f0);
        acc[0] += bf2f((short)v0.x) + bf2f((short)v1.x) + bf2f((short)v2.x) + bf2f((short)v3.x);
        acc[1] += bf2f((short)v0.y) + bf2f((short)v1.y) + bf2f((short)v2.y) + bf2f((short)v3.y);
        acc[2] += bf2f((short)v0.z) + bf2f((short)v1.z) + bf2f((short)v2.z) + bf2f((short)v3.z);
        acc[3] += bf2f((short)v0.w) + bf2f((short)v1.w) + bf2f((short)v2.w) + bf2f((short)v3.w);
    }
    for (; n < e; n++) {
        ushort4 v = *(const ushort4*)(h + (size_t)n * KP + f0);
        acc[0] += bf2f((short)v.x);
        acc[1] += bf2f((short)v.y);
        acc[2] += bf2f((short)v.z);
        acc[3] += bf2f((short)v.w);
    }
    *(float4*)(pooled + (size_t)g * FEAT + f0) = make_float4(acc[0], acc[1], acc[2], acc[3]);
}

__global__ void final_k(const float* __restrict__ pooled, const int* __restrict__ gstart,
                        const float* __restrict__ W_out, const float* __restrict__ b_out,
                        float* __restrict__ out) {
    int g = blockIdx.x >> 1, c = blockIdx.x & 1;
    int lane = threadIdx.x;  // 64
    float ssum = 0.f;
    for (int f = lane; f < FEAT; f += 64) ssum += pooled[(size_t)g * FEAT + f] * W_out[f * 2 + c];
#pragma unroll
    for (int o = 1; o < 64; o <<= 1) ssum += __shfl_xor(ssum, o);
    if (lane == 0) {
        float cnt = (float)(gstart[g + 1] - gstart[g]);
        float inv = 1.0f / fmaxf(cnt, 1.0f);
        out[g * 2 + c] = ssum * inv + b_out[c];
    }
}

// ---------------- launch ----------------
extern "C" void kernel_launch(void* const* d_in, const int* in_sizes, int n_in,
                              void* d_out, int out_size, void* d_ws, size_t ws_size,
                              hipStream_t stream) {
    const float* x       = (const float*)d_in[0];
    const int*   ei      = (const int*)d_in[1];
    const int*   batch   = (const int*)d_in[2];
    const float* W       = (const float*)d_in[3];
    const float* a_src   = (const float*)d_in[4];
    const float* a_dst   = (const float*)d_in[5];
    const float* b_att   = (const float*)d_in[6];
    const float* gamma   = (const float*)d_in[7];
    const float* beta    = (const float*)d_in[8];
    const float* r_mean  = (const float*)d_in[9];
    const float* r_var   = (const float*)d_in[10];
    const float* W_out   = (const float*)d_in[11];
    const float* b_out   = (const float*)d_in[12];
    float* out = (float*)d_out;

    const int N = in_sizes[0] / FEAT;
    const int E = in_sizes[1] / 2;
    const int E2 = E + N;
    const int MT = (N + 127) / 128;
    const int Mp = MT * 128;
    const int MTpad = ((MT + 7) / 8) * 8;

    char* w = (char*)d_ws;
    auto alloc = [&](size_t bytes) {
        void* pp = (void*)w;
        w += (bytes + 255) & ~(size_t)255;
        return pp;
    };
    short* xh_bf  = (short*)alloc((size_t)N * FEAT * 2);
    short* x_bf   = (short*)alloc((size_t)Mp * KP * 2);   // layer-0 A; reused as layer-3 h
    short* hA_bf  = (short*)alloc((size_t)Mp * KP * 2);
    short* hB_bf  = (short*)alloc((size_t)Mp * KP * 2);
    short* Bt3    = (short*)alloc((size_t)NLAYER * NP * KP * 2);
    float* asrc   = (float*)alloc((size_t)N * NHEAD * 4);
    float* adst   = (float*)alloc((size_t)N * NHEAD * 4);
    int*   src2   = (int*)alloc((size_t)E2 * 4);
    int*   dst2   = (int*)alloc((size_t)E2 * 4);
    int*   ssrc   = (int*)alloc((size_t)E2 * 4);
    int*   deg    = (int*)alloc((size_t)N * 4);
    int*   off    = (int*)alloc((size_t)(N + 1) * 4);
    int*   cursor = (int*)alloc((size_t)N * 4);
    int*   gstart = (int*)alloc((size_t)(NGRAPH + 1) * 4);
    float* pooled = (float*)alloc((size_t)NGRAPH * FEAT * 4);

    hipMemsetAsync(deg, 0, (size_t)N * 4, stream);
    hipMemsetAsync(Bt3, 0, (size_t)NLAYER * NP * KP * 2, stream);

    conv_x_bf<<<(N * FEAT + 255) / 256, 256, 0, stream>>>(x, x_bf, N);
    pad_bf<<<Mp, 64, 0, stream>>>(x_bf, N);
    pad_bf<<<Mp, 64, 0, stream>>>(hA_bf, N);
    pad_bf<<<Mp, 64, 0, stream>>>(hB_bf, N);
    dim3 tgrid((FEAT + 31) / 32, (FEAT + 31) / 32, NLAYER);
    transpose_w<<<tgrid, 256, 0, stream>>>(W, Bt3);
    wa_kernel<<<(NLAYER * FEAT * NHEAD + 255) / 256, 256, 0, stream>>>(W, a_src, a_dst, Bt3);

    build_edges<<<(E2 + 255) / 256, 256, 0, stream>>>(ei, E, N, src2, dst2, deg);
    scan_kernel<<<1, 1024, 0, stream>>>(deg, off, cursor, N);
    scatter_k<<<(E2 + 255) / 256, 256, 0, stream>>>(src2, dst2, cursor, ssrc, E2);
    gstart_k<<<(N + 255) / 256, 256, 0, stream>>>(batch, gstart, N);

    const short* hin[NLAYER]     = {x_bf, hA_bf, hB_bf};
    const float* prevf[NLAYER]   = {nullptr, x, nullptr};
    const short* prevbf[NLAYER]  = {nullptr, nullptr, hA_bf};
    short* houtl[NLAYER]         = {hA_bf, hB_bf, x_bf};

    for (int l = 0; l < NLAYER; l++) {
        gemm_mfma<<<MTpad * 9, 256, 0, stream>>>(hin[l], Bt3 + (size_t)l * NP * KP,
                                                 xh_bf, asrc, adst, N, MT);
        aggregate<<<N, 320, 0, stream>>>(xh_bf, off, ssrc, asrc, adst,
                                         prevf[l], prevbf[l],
                                         b_att + l * FEAT, gamma + l * FEAT, beta + l * FEAT,
                                         r_mean + l * FEAT, r_var + l * FEAT,
                                         houtl[l], N);
    }

    pool_k<<<NGRAPH, 320, 0, stream>>>(x_bf, gstart, pooled);
    final_k<<<NGRAPH * 2, 64, 0, stream>>>(pooled, gstart, W_out, b_out, out);
}